// Round 5
// baseline (213.548 us; speedup 1.0000x reference)
//
#include <hip/hip_runtime.h>
#include <hip/hip_bf16.h>
#include <cstdint>

// GQA prefill: b=2, t=1024, E=2048, NQ=32, NKV=8, HD=64. fp32 in/out, bf16 MFMA inside.

typedef __attribute__((ext_vector_type(8))) short short8;   // 8 bf16 (MFMA A/B frag)
typedef __attribute__((ext_vector_type(4))) short short4v;
typedef __attribute__((ext_vector_type(4))) float f32x4;    // MFMA C/D frag

__device__ inline short f2b(float f) {  // fp32 -> bf16 (RNE)
  union { float f; unsigned u; } v; v.f = f;
  unsigned r = v.u + 0x7fffu + ((v.u >> 16) & 1u);
  return (short)(r >> 16);
}

__device__ inline float exp2_fast(float x) {
  float r;
  asm("v_exp_f32 %0, %1" : "=v"(r) : "v"(x));
  return r;
}

__device__ inline void gl_lds16(const void* g, void* l) {
  // async global->LDS, 16B/lane; LDS dest = wave-uniform base + lane*16
  __builtin_amdgcn_global_load_lds((const __attribute__((address_space(1))) void*)g,
                                   (__attribute__((address_space(3))) void*)l,
                                   16, 0, 0);
}

// ---------------- elementwise cast x -> bf16 ----------------
__global__ void cast_x_kernel(const float* __restrict__ x, short* __restrict__ xb, int n4) {
  int i = blockIdx.x * 256 + threadIdx.x;
  if (i >= n4) return;
  float4 v = ((const float4*)x)[i];
  short4v o; o.x = f2b(v.x); o.y = f2b(v.y); o.z = f2b(v.z); o.w = f2b(v.w);
  ((short4v*)xb)[i] = o;
}

// ---------------- all weight transposes in one launch ----------------
// grid (80, 32): x<32 wq | <40 wk | <48 wv | else wo. 64x64 LDS tile each.
__global__ void wtrans_all(const float* __restrict__ wq, const float* __restrict__ wk,
                           const float* __restrict__ wv, const float* __restrict__ wo,
                           short* __restrict__ WqkvT, short* __restrict__ woT) {
  __shared__ float tile[64][65];
  const int bx = blockIdx.x;
  const float* W; short* WT; int N, off, nb;
  if (bx < 32)      { W = wq; WT = WqkvT; N = 2048; off = 0;    nb = bx * 64; }
  else if (bx < 40) { W = wk; WT = WqkvT; N = 512;  off = 2048; nb = (bx - 32) * 64; }
  else if (bx < 48) { W = wv; WT = WqkvT; N = 512;  off = 2560; nb = (bx - 40) * 64; }
  else              { W = wo; WT = woT;   N = 2048; off = 0;    nb = (bx - 48) * 64; }
  const int kb = blockIdx.y * 64;
  const int tid = threadIdx.x;
  const int c = tid & 63, r0 = tid >> 6;
#pragma unroll
  for (int s = 0; s < 16; ++s) {
    int k = r0 + s * 4;
    tile[c][k] = W[(size_t)(kb + k) * N + nb + c];
  }
  __syncthreads();
#pragma unroll
  for (int s = 0; s < 16; ++s) {
    int n = r0 + s * 4;
    WT[(size_t)(off + nb + n) * 2048 + kb + c] = f2b(tile[n][c]);
  }
}

// ---------------- shared K-loop: 128(M)x64(N) tile, K=2048, BK=64, double-buffered ----------
// R0 structure (measured best: ~42us for QKV): one __syncthreads per BK=64 stage,
// 32 barriers, per wave per stage 6 gl_lds + 12 ds_read_b128 + 16 MFMA.
// lA: 2 bufs x 2 k-panels x [128][32] = 16384 shorts; lB: 2 x 2 x [64][32] = 8192.
// T2 swizzle (verified, conflicts 4.7M->0): LDS stays linear; the GLOBAL source
// column is pre-swizzled (swzc in callers), reads use q4x = q4 ^ ((l15>>1)&3).
__device__ __forceinline__ void gemm_loop_bk64(const short* __restrict__ Ag,
                                               const short* __restrict__ Bg,
                                               short* lA, short* lB,
                                               int w, int l15, int q4,
                                               f32x4 acc[2][4]) {
  const int K = 2048, NS = 32;  // stages of BK=64
  const int q4x = q4 ^ ((l15 >> 1) & 3);  // swizzled k-slot for LDS reads
  auto stage = [&](int s, int d) {
    const short* As = Ag + s * 64;
    const short* Bs = Bg + s * 64;
    short* a = lA + d * 8192 + w * 512;
    gl_lds16(As, a);                          // panel0 rows [w*16,+16)
    gl_lds16(As + 64 * K, a + 2048);          // panel0 rows +64
    gl_lds16(As + 32, a + 4096);              // panel1 rows [w*16,+16)
    gl_lds16(As + 64 * K + 32, a + 6144);     // panel1 rows +64
    short* bp = lB + d * 4096 + w * 512;
    gl_lds16(Bs, bp);                         // panel0
    gl_lds16(Bs + 32, bp + 2048);             // panel1
  };
  stage(0, 0);
  for (int s = 0; s < NS; ++s) {
    const int d = s & 1;
    __syncthreads();                          // drains stage(s) loads; frees buf d^1
    if (s + 1 < NS) stage(s + 1, d ^ 1);      // prefetch next stage (drained at NEXT barrier)
#pragma unroll
    for (int ks = 0; ks < 2; ++ks) {
      const short* ap = lA + d * 8192 + ks * 4096;
      const short* bp = lB + d * 4096 + ks * 2048;
      short8 af[2], bf[4];
#pragma unroll
      for (int mf = 0; mf < 2; ++mf) af[mf] = *(const short8*)(ap + (w * 32 + mf * 16 + l15) * 32 + q4x * 8);
#pragma unroll
      for (int nf = 0; nf < 4; ++nf) bf[nf] = *(const short8*)(bp + (nf * 16 + l15) * 32 + q4x * 8);
#pragma unroll
      for (int mf = 0; mf < 2; ++mf)
#pragma unroll
        for (int nf = 0; nf < 4; ++nf)
          acc[mf][nf] = __builtin_amdgcn_mfma_f32_16x16x32_bf16(af[mf], bf[nf], acc[mf][nf], 0, 0, 0);
    }
  }
}

// ---------------- fused QKV GEMM + bias + RoPE + scatter epilogue ----------------
// V-epilogue writes the VT panel layout directly (no vtrans kernel).
__launch_bounds__(256, 3)
__global__ void gemm_qkv(const short* __restrict__ A, const short* __restrict__ BT,
                         const float* __restrict__ bq, const float* __restrict__ bk,
                         const float* __restrict__ bv,
                         short* __restrict__ Qb, short* __restrict__ Kb,
                         short* __restrict__ VTb) {
  __shared__ __align__(16) short lA[16384];
  __shared__ __align__(16) short lB[8192];
  const int K = 2048;
  const int tid = threadIdx.x, lane = tid & 63, w = tid >> 6;
  const int q4 = lane >> 4, l15 = lane & 15;
  const int bn = blockIdx.x * 64, bm = blockIdx.y * 128;

  // staging source: swizzled k-slot (see gemm_loop_bk64 header comment)
  const int swzc = ((tid & 3) ^ ((tid >> 3) & 3)) << 3;
  const short* Ag = A + (size_t)(bm + (tid >> 2)) * K + swzc;
  const short* Bg = BT + (size_t)(bn + (tid >> 2)) * K + swzc;

  f32x4 acc[2][4];
  const f32x4 fz = {0.f, 0.f, 0.f, 0.f};
#pragma unroll
  for (int i = 0; i < 2; ++i)
#pragma unroll
    for (int j = 0; j < 4; ++j) acc[i][j] = fz;

  gemm_loop_bk64(Ag, Bg, lA, lB, w, l15, q4, acc);

  // ----- epilogue -----
  const float L2T = 0.4152410118609203f;          // log2(10000)/32
  const float theta_a = exp2_fast(-(float)l15 * L2T);
  const float theta_b = exp2_fast(-(float)(l15 + 16) * L2T);
  const float s2 = 0.18033688011112042f;          // 0.125 * log2(e): base-2 attn scores

  if (bn < 2048) {            // ---- Q: rope + scale -> Qb (b,h,t,64)
    const int h = bn >> 6;
    float bb0 = bq[bn + l15], bb1 = bq[bn + 16 + l15], bb2 = bq[bn + 32 + l15], bb3 = bq[bn + 48 + l15];
#pragma unroll
    for (int mf = 0; mf < 2; ++mf)
#pragma unroll
      for (int r = 0; r < 4; ++r) {
        int row = bm + w * 32 + mf * 16 + q4 * 4 + r;
        int batch = row >> 10, t = row & 1023;
        float pos = (float)(t + 1);
        float sa, ca, sb, cb;
        __sincosf(pos * theta_a, &sa, &ca);
        __sincosf(pos * theta_b, &sb, &cb);
        float x0 = acc[mf][0][r] + bb0, x2 = acc[mf][2][r] + bb2;
        float x1 = acc[mf][1][r] + bb1, x3 = acc[mf][3][r] + bb3;
        size_t base = ((size_t)(batch * 32 + h) * 1024 + t) * 64;
        Qb[base + l15]      = f2b((x0 * ca - x2 * sa) * s2);
        Qb[base + l15 + 32] = f2b((x2 * ca + x0 * sa) * s2);
        Qb[base + l15 + 16] = f2b((x1 * cb - x3 * sb) * s2);
        Qb[base + l15 + 48] = f2b((x3 * cb + x1 * sb) * s2);
      }
  } else if (bn < 2560) {     // ---- K: rope -> Kb (b,hkv)[dhalf][t][32]
    const int co = bn - 2048;
    const int hkv = co >> 6;
    float bb0 = bk[co + l15], bb1 = bk[co + 16 + l15], bb2 = bk[co + 32 + l15], bb3 = bk[co + 48 + l15];
#pragma unroll
    for (int mf = 0; mf < 2; ++mf)
#pragma unroll
      for (int r = 0; r < 4; ++r) {
        int row = bm + w * 32 + mf * 16 + q4 * 4 + r;
        int batch = row >> 10, t = row & 1023;
        float pos = (float)(t + 1);
        float sa, ca, sb, cb;
        __sincosf(pos * theta_a, &sa, &ca);
        __sincosf(pos * theta_b, &sb, &cb);
        float x0 = acc[mf][0][r] + bb0, x2 = acc[mf][2][r] + bb2;
        float x1 = acc[mf][1][r] + bb1, x3 = acc[mf][3][r] + bb3;
        size_t base = (size_t)(batch * 8 + hkv) * 65536 + t * 32;
        Kb[base + l15]              = f2b(x0 * ca - x2 * sa);  // d=l15      (half0)
        Kb[base + l15 + 16]         = f2b(x1 * cb - x3 * sb);  // d=l15+16   (half0)
        Kb[base + 32768 + l15]      = f2b(x2 * ca + x0 * sa);  // d=l15+32   (half1)
        Kb[base + 32768 + l15 + 16] = f2b(x3 * cb + x1 * sb);  // d=l15+48   (half1)
      }
  } else {                    // ---- V: bias -> VTb (b,hkv)[tchunk32][d64][32] directly
    const int co = bn - 2560;
    const int hkv = co >> 6;
    float bb[4];
#pragma unroll
    for (int nf = 0; nf < 4; ++nf) bb[nf] = bv[co + nf * 16 + l15];
    const int batch = (bm + w * 32) >> 10;          // bm%128==0, w*32<128: no crossing
    const size_t vbase = (size_t)(batch * 8 + hkv) * 65536;
#pragma unroll
    for (int mf = 0; mf < 2; ++mf) {
      const int t0 = (bm + w * 32 + mf * 16 + q4 * 4) & 1023;
      // t0&31 = mf*16+q4*4 <= 28, so r=0..3 stays inside the 32-chunk
      const size_t rbase = vbase + (size_t)(t0 >> 5) * 2048 + (t0 & 31);
#pragma unroll
      for (int nf = 0; nf < 4; ++nf) {
        short4v pk;
#pragma unroll
        for (int r = 0; r < 4; ++r) pk[r] = f2b(acc[mf][nf][r] + bb[nf]);
        *(short4v*)(VTb + rbase + (nf * 16 + l15) * 32) = pk;
      }
    }
  }
}

// ---------------- flash attention v7: barrier-free loop + intra-block k-split x4 ----------------
// The q axis yields only 2048 waves (2/SIMD, no backfill) -> latency-bound tail.
// Fix: 4 waves per block, wave w handles ktg = w, w+4, ...  The fixed-shift
// softmax state (o, ol) is LINEAR in k-tiles, so partials just add: one barrier,
// waves 1-3 dump (o,ol) to LDS f32, wave 0 sums, divides, writes AO.
// 8192 waves total, ~3 resident/SIMD (VGPR) + backfill pool for the causal tail.
#define PROW 72
__launch_bounds__(256, 2)
__global__ void attn7_kernel(const short* __restrict__ Qb, const short* __restrict__ Kb,
                             const short* __restrict__ VTb, short* __restrict__ AO) {
  // lP (loop phase): 4 waves x [2][16*PROW] shorts = 18432 B
  // cf (combine phase, after full-block barrier): [3][32][65] f32 = 24960 B
  __shared__ __align__(16) char lmem[25088];
  const int tid = threadIdx.x, lane = tid & 63, w = tid >> 6;
  const int q4 = lane >> 4, l15 = lane & 15;
  const int qt = 31 - (int)blockIdx.x;  // heavy blocks dispatched first
  const int h = blockIdx.y, b = blockIdx.z;
  const int hkv = h >> 2;
  const int qb = qt * 32;
  const int kdiag = qb >> 6;            // diagonal 64-col tile index

  short* lPw = (short*)lmem + w * 2 * 16 * PROW;   // this wave's P buffer
  float (*cf)[32][65] = (float(*)[32][65])lmem;    // combine region (post-barrier)

  const short* Qg = Qb + (size_t)(b * 32 + h) * 65536;
  const short* Kg = Kb + (size_t)(b * 8 + hkv) * 65536;
  const short* Vg = VTb + (size_t)(b * 8 + hkv) * 65536;

  short8 qf[2][2];
#pragma unroll
  for (int mf = 0; mf < 2; ++mf) {
    const short* qr = Qg + (size_t)(qb + mf * 16 + l15) * 64 + q4 * 8;
    qf[mf][0] = *(const short8*)(qr);
    qf[mf][1] = *(const short8*)(qr + 32);
  }

  const f32x4 fz = {0.f, 0.f, 0.f, 0.f};
  f32x4 o[2][4], ol[2];
#pragma unroll
  for (int mf = 0; mf < 2; ++mf) {
    ol[mf] = fz;
#pragma unroll
    for (int i = 0; i < 4; ++i) o[mf][i] = fz;
  }
  short8 ones;
#pragma unroll
  for (int i = 0; i < 8; ++i) ones[i] = (short)0x3F80;

  short8 kf0[4], kf1[4], vf0[4], vf1[4];
  auto loadK = [&](int ktg) {
    const short* kb0 = Kg + (size_t)(ktg * 64 + l15) * 32 + q4 * 8;
#pragma unroll
    for (int nt = 0; nt < 4; ++nt) kf0[nt] = *(const short8*)(kb0 + nt * 512);
#pragma unroll
    for (int nt = 0; nt < 4; ++nt) kf1[nt] = *(const short8*)(kb0 + 32768 + nt * 512);
  };
  auto loadV = [&](int ktg) {
    const short* vb = Vg + (size_t)(2 * ktg) * 2048 + l15 * 32 + q4 * 8;
#pragma unroll
    for (int dt = 0; dt < 4; ++dt) vf0[dt] = *(const short8*)(vb + dt * 512);
#pragma unroll
    for (int dt = 0; dt < 4; ++dt) vf1[dt] = *(const short8*)(vb + 2048 + dt * 512);
  };

  if (w <= kdiag) loadK(w);
  for (int ktg = w; ktg <= kdiag; ktg += 4) {
    loadV(ktg);                         // issue V loads (consumed by PV below)
    // ---- QK^T (consumes kf preloaded for this ktg) ----
    f32x4 sv[2][4];
#pragma unroll
    for (int mf = 0; mf < 2; ++mf)
#pragma unroll
      for (int nt = 0; nt < 4; ++nt) {
        f32x4 z = __builtin_amdgcn_mfma_f32_16x16x32_bf16(qf[mf][0], kf0[nt], fz, 0, 0, 0);
        sv[mf][nt] = __builtin_amdgcn_mfma_f32_16x16x32_bf16(qf[mf][1], kf1[nt], z, 0, 0, 0);
      }
    if (ktg == kdiag) {                 // causal mask on the diagonal tile
#pragma unroll
      for (int mf = 0; mf < 2; ++mf)
#pragma unroll
        for (int r = 0; r < 4; ++r) {
          const int qrow = qb + mf * 16 + q4 * 4 + r;
          const int col = ktg * 64 + l15;
#pragma unroll
          for (int nt = 0; nt < 4; ++nt)
            if (col + nt * 16 > qrow) sv[mf][nt][r] = -1e30f;
        }
    }
    if (ktg + 4 <= kdiag) loadK(ktg + 4);  // prefetch this wave's next K-tile
    // ---- softmax (fixed-shift, linear state) -> per-wave lP ----
#pragma unroll
    for (int mf = 0; mf < 2; ++mf) {
      short* lPm = lPw + mf * 16 * PROW;
#pragma unroll
      for (int r = 0; r < 4; ++r)
#pragma unroll
        for (int nt = 0; nt < 4; ++nt)
          lPm[(q4 * 4 + r) * PROW + nt * 16 + l15] = f2b(exp2_fast(sv[mf][nt][r] - 16.f));
    }
    // ---- PV (waits V loads; next-K stays in flight) ----
#pragma unroll
    for (int mf = 0; mf < 2; ++mf) {
      const short* lPm = lPw + mf * 16 * PROW;
      short8 pf0 = *(const short8*)(lPm + l15 * PROW + q4 * 8);
      short8 pf1 = *(const short8*)(lPm + l15 * PROW + 32 + q4 * 8);
      ol[mf] = __builtin_amdgcn_mfma_f32_16x16x32_bf16(pf0, ones, ol[mf], 0, 0, 0);
      ol[mf] = __builtin_amdgcn_mfma_f32_16x16x32_bf16(pf1, ones, ol[mf], 0, 0, 0);
#pragma unroll
      for (int dt = 0; dt < 4; ++dt) {
        o[mf][dt] = __builtin_amdgcn_mfma_f32_16x16x32_bf16(pf0, vf0[dt], o[mf][dt], 0, 0, 0);
        o[mf][dt] = __builtin_amdgcn_mfma_f32_16x16x32_bf16(pf1, vf1[dt], o[mf][dt], 0, 0, 0);
      }
    }
  }

  // ---- combine: waves 1-3 dump partials; wave 0 sums + writes ----
  __syncthreads();                      // all waves done with lP region
  if (w > 0) {
#pragma unroll
    for (int mf = 0; mf < 2; ++mf)
#pragma unroll
      for (int r = 0; r < 4; ++r) {
        const int row = mf * 16 + q4 * 4 + r;
#pragma unroll
        for (int dt = 0; dt < 4; ++dt) cf[w - 1][row][dt * 16 + l15] = o[mf][dt][r];
        if (l15 == 0) cf[w - 1][row][64] = ol[mf][r];
      }
  }
  __syncthreads();
  if (w == 0) {
#pragma unroll
    for (int mf = 0; mf < 2; ++mf)
#pragma unroll
      for (int r = 0; r < 4; ++r) {
        const int row = mf * 16 + q4 * 4 + r;
        float olsum = ol[mf][r] + cf[0][row][64] + cf[1][row][64] + cf[2][row][64];
        float inv = __builtin_amdgcn_rcpf(olsum);
        const int grow = qb + row;
#pragma unroll
        for (int dt = 0; dt < 4; ++dt) {
          float v = o[mf][dt][r] + cf[0][row][dt * 16 + l15] + cf[1][row][dt * 16 + l15]
                    + cf[2][row][dt * 16 + l15];
          AO[(size_t)(b * 1024 + grow) * 2048 + h * 64 + dt * 16 + l15] = f2b(v * inv);
        }
      }
  }
}

// ---------------- output projection: BK=64 double-buffered, fp32 out + bias ----------------
__launch_bounds__(256, 3)
__global__ void gemm_out(const short* __restrict__ A, const short* __restrict__ BT,
                         float* __restrict__ C, const float* __restrict__ bias,
                         int N, int K) {
  __shared__ __align__(16) short lA[16384];
  __shared__ __align__(16) short lB[8192];
  const int tid = threadIdx.x, lane = tid & 63, w = tid >> 6;
  const int q4 = lane >> 4, l15 = lane & 15;
  const int bn = blockIdx.x * 64, bm = blockIdx.y * 128;

  const int swzc = ((tid & 3) ^ ((tid >> 3) & 3)) << 3;
  const short* Ag = A + (size_t)(bm + (tid >> 2)) * K + swzc;
  const short* Bg = BT + (size_t)(bn + (tid >> 2)) * K + swzc;

  f32x4 acc[2][4];
  const f32x4 fz = {0.f, 0.f, 0.f, 0.f};
#pragma unroll
  for (int i = 0; i < 2; ++i)
#pragma unroll
    for (int j = 0; j < 4; ++j) acc[i][j] = fz;

  gemm_loop_bk64(Ag, Bg, lA, lB, w, l15, q4, acc);

#pragma unroll
  for (int mf = 0; mf < 2; ++mf)
#pragma unroll
    for (int nf = 0; nf < 4; ++nf) {
      int col = bn + nf * 16 + l15;
      float bb = bias[col];
#pragma unroll
      for (int r = 0; r < 4; ++r) {
        int row = bm + w * 32 + mf * 16 + q4 * 4 + r;
        C[(size_t)row * N + col] = acc[mf][nf][r] + bb;
      }
    }
}

extern "C" void kernel_launch(void* const* d_in, const int* in_sizes, int n_in,
                              void* d_out, int out_size, void* d_ws, size_t ws_size,
                              hipStream_t stream) {
  const float* x  = (const float*)d_in[0];
  const float* wq = (const float*)d_in[1];
  const float* bq = (const float*)d_in[2];
  const float* wk = (const float*)d_in[3];
  const float* bk = (const float*)d_in[4];
  const float* wv = (const float*)d_in[5];
  const float* bv = (const float*)d_in[6];
  const float* wo = (const float*)d_in[7];
  const float* bo = (const float*)d_in[8];
  float* out = (float*)d_out;
  const int B = in_sizes[0] / (1024 * 2048);
  const int M = B * 1024;

  char* ws = (char*)d_ws;
  size_t off = 0;
  auto alloc = [&](size_t bytes) -> char* {
    char* p = ws + off;
    off += (bytes + 255) & ~(size_t)255;
    return p;
  };
  short* xb    = (short*)alloc((size_t)M * 2048 * 2);
  short* WqkvT = (short*)alloc((size_t)3072 * 2048 * 2);  // rows: wq^T | wk^T | wv^T (K-major)
  short* woT   = (short*)alloc((size_t)2048 * 2048 * 2);
  short* Qb    = (short*)alloc((size_t)B * 32 * 1024 * 64 * 2);    // (b,h,t,d)
  short* Kb    = (short*)alloc((size_t)B * 8 * 2 * 1024 * 32 * 2); // (b,hkv)[dhalf][t][32]
  short* VTb   = (short*)alloc((size_t)B * 8 * 32 * 64 * 32 * 2);  // (b,hkv)[tchunk][d][32]
  short* AO    = (short*)alloc((size_t)M * 2048 * 2);              // (b,t,E) bf16

  cast_x_kernel<<<(M * 2048 / 4 + 255) / 256, 256, 0, stream>>>(x, xb, M * 2048 / 4);
  wtrans_all<<<dim3(80, 32), 256, 0, stream>>>(wq, wk, wv, wo, WqkvT, woT);
  gemm_qkv<<<dim3(48, M / 128), 256, 0, stream>>>(xb, WqkvT, bq, bk, bv, Qb, Kb, VTb);
  attn7_kernel<<<dim3(32, 32, B), 256, 0, stream>>>(Qb, Kb, VTb, AO);
  gemm_out<<<dim3(32, M / 128), 256, 0, stream>>>(AO, woT, out, bo, 2048, 2048);
}

// Round 6
// 206.622 us; speedup vs baseline: 1.0335x; 1.0335x over previous
//
#include <hip/hip_runtime.h>
#include <hip/hip_bf16.h>
#include <cstdint>

// GQA prefill: b=2, t=1024, E=2048, NQ=32, NKV=8, HD=64. fp32 in/out, bf16 MFMA inside.

typedef __attribute__((ext_vector_type(8))) short short8;   // 8 bf16 (MFMA A/B frag)
typedef __attribute__((ext_vector_type(4))) short short4v;
typedef __attribute__((ext_vector_type(4))) float f32x4;    // MFMA C/D frag

__device__ inline short f2b(float f) {  // fp32 -> bf16 (RNE)
  union { float f; unsigned u; } v; v.f = f;
  unsigned r = v.u + 0x7fffu + ((v.u >> 16) & 1u);
  return (short)(r >> 16);
}

__device__ inline float exp2_fast(float x) {
  float r;
  asm("v_exp_f32 %0, %1" : "=v"(r) : "v"(x));
  return r;
}

__device__ inline void gl_lds16(const void* g, void* l) {
  // async global->LDS, 16B/lane; LDS dest = wave-uniform base + lane*16
  __builtin_amdgcn_global_load_lds((const __attribute__((address_space(1))) void*)g,
                                   (__attribute__((address_space(3))) void*)l,
                                   16, 0, 0);
}

// ---------------- elementwise cast x -> bf16 ----------------
__global__ void cast_x_kernel(const float* __restrict__ x, short* __restrict__ xb, int n4) {
  int i = blockIdx.x * 256 + threadIdx.x;
  if (i >= n4) return;
  float4 v = ((const float4*)x)[i];
  short4v o; o.x = f2b(v.x); o.y = f2b(v.y); o.z = f2b(v.z); o.w = f2b(v.w);
  ((short4v*)xb)[i] = o;
}

// ---------------- all weight transposes in one launch ----------------
// grid (80, 32): x<32 wq | <40 wk | <48 wv | else wo. 64x64 LDS tile each.
__global__ void wtrans_all(const float* __restrict__ wq, const float* __restrict__ wk,
                           const float* __restrict__ wv, const float* __restrict__ wo,
                           short* __restrict__ WqkvT, short* __restrict__ woT) {
  __shared__ float tile[64][65];
  const int bx = blockIdx.x;
  const float* W; short* WT; int N, off, nb;
  if (bx < 32)      { W = wq; WT = WqkvT; N = 2048; off = 0;    nb = bx * 64; }
  else if (bx < 40) { W = wk; WT = WqkvT; N = 512;  off = 2048; nb = (bx - 32) * 64; }
  else if (bx < 48) { W = wv; WT = WqkvT; N = 512;  off = 2560; nb = (bx - 40) * 64; }
  else              { W = wo; WT = woT;   N = 2048; off = 0;    nb = (bx - 48) * 64; }
  const int kb = blockIdx.y * 64;
  const int tid = threadIdx.x;
  const int c = tid & 63, r0 = tid >> 6;
#pragma unroll
  for (int s = 0; s < 16; ++s) {
    int k = r0 + s * 4;
    tile[c][k] = W[(size_t)(kb + k) * N + nb + c];
  }
  __syncthreads();
#pragma unroll
  for (int s = 0; s < 16; ++s) {
    int n = r0 + s * 4;
    WT[(size_t)(off + nb + n) * 2048 + kb + c] = f2b(tile[n][c]);
  }
}

// ---------------- shared K-loop: 128(M)x64(N) tile, K=2048, BK=64, double-buffered ----------
// R0 structure (measured best: ~42us for QKV): one __syncthreads per BK=64 stage,
// 32 barriers, per wave per stage 6 gl_lds + 12 ds_read_b128 + 16 MFMA.
// lA: 2 bufs x 2 k-panels x [128][32] = 16384 shorts; lB: 2 x 2 x [64][32] = 8192.
// T2 swizzle (verified, conflicts 4.7M->0): LDS stays linear; the GLOBAL source
// column is pre-swizzled (swzc in callers), reads use q4x = q4 ^ ((l15>>1)&3).
__device__ __forceinline__ void gemm_loop_bk64(const short* __restrict__ Ag,
                                               const short* __restrict__ Bg,
                                               short* lA, short* lB,
                                               int w, int l15, int q4,
                                               f32x4 acc[2][4]) {
  const int K = 2048, NS = 32;  // stages of BK=64
  const int q4x = q4 ^ ((l15 >> 1) & 3);  // swizzled k-slot for LDS reads
  auto stage = [&](int s, int d) {
    const short* As = Ag + s * 64;
    const short* Bs = Bg + s * 64;
    short* a = lA + d * 8192 + w * 512;
    gl_lds16(As, a);                          // panel0 rows [w*16,+16)
    gl_lds16(As + 64 * K, a + 2048);          // panel0 rows +64
    gl_lds16(As + 32, a + 4096);              // panel1 rows [w*16,+16)
    gl_lds16(As + 64 * K + 32, a + 6144);     // panel1 rows +64
    short* bp = lB + d * 4096 + w * 512;
    gl_lds16(Bs, bp);                         // panel0
    gl_lds16(Bs + 32, bp + 2048);             // panel1
  };
  stage(0, 0);
  for (int s = 0; s < NS; ++s) {
    const int d = s & 1;
    __syncthreads();                          // drains stage(s) loads; frees buf d^1
    if (s + 1 < NS) stage(s + 1, d ^ 1);      // prefetch next stage (drained at NEXT barrier)
#pragma unroll
    for (int ks = 0; ks < 2; ++ks) {
      const short* ap = lA + d * 8192 + ks * 4096;
      const short* bp = lB + d * 4096 + ks * 2048;
      short8 af[2], bf[4];
#pragma unroll
      for (int mf = 0; mf < 2; ++mf) af[mf] = *(const short8*)(ap + (w * 32 + mf * 16 + l15) * 32 + q4x * 8);
#pragma unroll
      for (int nf = 0; nf < 4; ++nf) bf[nf] = *(const short8*)(bp + (nf * 16 + l15) * 32 + q4x * 8);
#pragma unroll
      for (int mf = 0; mf < 2; ++mf)
#pragma unroll
        for (int nf = 0; nf < 4; ++nf)
          acc[mf][nf] = __builtin_amdgcn_mfma_f32_16x16x32_bf16(af[mf], bf[nf], acc[mf][nf], 0, 0, 0);
    }
  }
}

// ---------------- fused QKV GEMM + bias + RoPE + scatter epilogue ----------------
// V-epilogue writes the VT panel layout directly (no vtrans kernel).
__launch_bounds__(256, 3)
__global__ void gemm_qkv(const short* __restrict__ A, const short* __restrict__ BT,
                         const float* __restrict__ bq, const float* __restrict__ bk,
                         const float* __restrict__ bv,
                         short* __restrict__ Qb, short* __restrict__ Kb,
                         short* __restrict__ VTb) {
  __shared__ __align__(16) short lA[16384];
  __shared__ __align__(16) short lB[8192];
  const int K = 2048;
  const int tid = threadIdx.x, lane = tid & 63, w = tid >> 6;
  const int q4 = lane >> 4, l15 = lane & 15;
  const int bn = blockIdx.x * 64, bm = blockIdx.y * 128;

  // staging source: swizzled k-slot (see gemm_loop_bk64 header comment)
  const int swzc = ((tid & 3) ^ ((tid >> 3) & 3)) << 3;
  const short* Ag = A + (size_t)(bm + (tid >> 2)) * K + swzc;
  const short* Bg = BT + (size_t)(bn + (tid >> 2)) * K + swzc;

  f32x4 acc[2][4];
  const f32x4 fz = {0.f, 0.f, 0.f, 0.f};
#pragma unroll
  for (int i = 0; i < 2; ++i)
#pragma unroll
    for (int j = 0; j < 4; ++j) acc[i][j] = fz;

  gemm_loop_bk64(Ag, Bg, lA, lB, w, l15, q4, acc);

  // ----- epilogue -----
  const float L2T = 0.4152410118609203f;          // log2(10000)/32
  const float theta_a = exp2_fast(-(float)l15 * L2T);
  const float theta_b = exp2_fast(-(float)(l15 + 16) * L2T);
  const float s2 = 0.18033688011112042f;          // 0.125 * log2(e): base-2 attn scores

  if (bn < 2048) {            // ---- Q: rope + scale -> Qb (b,h,t,64)
    const int h = bn >> 6;
    float bb0 = bq[bn + l15], bb1 = bq[bn + 16 + l15], bb2 = bq[bn + 32 + l15], bb3 = bq[bn + 48 + l15];
#pragma unroll
    for (int mf = 0; mf < 2; ++mf)
#pragma unroll
      for (int r = 0; r < 4; ++r) {
        int row = bm + w * 32 + mf * 16 + q4 * 4 + r;
        int batch = row >> 10, t = row & 1023;
        float pos = (float)(t + 1);
        float sa, ca, sb, cb;
        __sincosf(pos * theta_a, &sa, &ca);
        __sincosf(pos * theta_b, &sb, &cb);
        float x0 = acc[mf][0][r] + bb0, x2 = acc[mf][2][r] + bb2;
        float x1 = acc[mf][1][r] + bb1, x3 = acc[mf][3][r] + bb3;
        size_t base = ((size_t)(batch * 32 + h) * 1024 + t) * 64;
        Qb[base + l15]      = f2b((x0 * ca - x2 * sa) * s2);
        Qb[base + l15 + 32] = f2b((x2 * ca + x0 * sa) * s2);
        Qb[base + l15 + 16] = f2b((x1 * cb - x3 * sb) * s2);
        Qb[base + l15 + 48] = f2b((x3 * cb + x1 * sb) * s2);
      }
  } else if (bn < 2560) {     // ---- K: rope -> Kb (b,hkv)[dhalf][t][32]
    const int co = bn - 2048;
    const int hkv = co >> 6;
    float bb0 = bk[co + l15], bb1 = bk[co + 16 + l15], bb2 = bk[co + 32 + l15], bb3 = bk[co + 48 + l15];
#pragma unroll
    for (int mf = 0; mf < 2; ++mf)
#pragma unroll
      for (int r = 0; r < 4; ++r) {
        int row = bm + w * 32 + mf * 16 + q4 * 4 + r;
        int batch = row >> 10, t = row & 1023;
        float pos = (float)(t + 1);
        float sa, ca, sb, cb;
        __sincosf(pos * theta_a, &sa, &ca);
        __sincosf(pos * theta_b, &sb, &cb);
        float x0 = acc[mf][0][r] + bb0, x2 = acc[mf][2][r] + bb2;
        float x1 = acc[mf][1][r] + bb1, x3 = acc[mf][3][r] + bb3;
        size_t base = (size_t)(batch * 8 + hkv) * 65536 + t * 32;
        Kb[base + l15]              = f2b(x0 * ca - x2 * sa);  // d=l15      (half0)
        Kb[base + l15 + 16]         = f2b(x1 * cb - x3 * sb);  // d=l15+16   (half0)
        Kb[base + 32768 + l15]      = f2b(x2 * ca + x0 * sa);  // d=l15+32   (half1)
        Kb[base + 32768 + l15 + 16] = f2b(x3 * cb + x1 * sb);  // d=l15+48   (half1)
      }
  } else {                    // ---- V: bias -> VTb (b,hkv)[tchunk32][d64][32] directly
    const int co = bn - 2560;
    const int hkv = co >> 6;
    float bb[4];
#pragma unroll
    for (int nf = 0; nf < 4; ++nf) bb[nf] = bv[co + nf * 16 + l15];
    const int batch = (bm + w * 32) >> 10;          // bm%128==0, w*32<128: no crossing
    const size_t vbase = (size_t)(batch * 8 + hkv) * 65536;
#pragma unroll
    for (int mf = 0; mf < 2; ++mf) {
      const int t0 = (bm + w * 32 + mf * 16 + q4 * 4) & 1023;
      // t0&31 = mf*16+q4*4 <= 28, so r=0..3 stays inside the 32-chunk
      const size_t rbase = vbase + (size_t)(t0 >> 5) * 2048 + (t0 & 31);
#pragma unroll
      for (int nf = 0; nf < 4; ++nf) {
        short4v pk;
#pragma unroll
        for (int r = 0; r < 4; ++r) pk[r] = f2b(acc[mf][nf][r] + bb[nf]);
        *(short4v*)(VTb + rbase + (nf * 16 + l15) * 32) = pk;
      }
    }
  }
}

// ---------------- flash attention v8: attn5 + double-buffered K/V staging ----------------
// Identical to the best-measured attn5 (41.6us) except: 64-col stages, 2 LDS bufs,
// and stage(s+1) is issued AFTER the barrier and BEFORE compute(s) (m97 overlap
// pattern, same as gemm_loop_bk64) -- staging L2 latency hides under QK/PV MFMA.
// One __syncthreads per 64-col stage (same total barrier count as attn5).
// grid (8, 32, B); block = 128 q-rows; wave w owns rows [qt*128+w*32, +32).
// Fixed-shift softmax P=2^(s2-16) (linear state); T2 swizzle on K/V tiles.
#define PROW 72
__launch_bounds__(256, 3)
__global__ void attn8_kernel(const short* __restrict__ Qb, const short* __restrict__ Kb,
                             const short* __restrict__ VTb, short* __restrict__ AO) {
  __shared__ __align__(16) short lK[2][2 * 64 * 32];   // [dbuf][dhalf][krow][32]
  __shared__ __align__(16) short lVT[2][2 * 64 * 32];  // [dbuf][tchunk][d][32]
  __shared__ __align__(16) short lP[4][2][16 * PROW];
  const int tid = threadIdx.x, lane = tid & 63, w = tid >> 6;
  const int q4 = lane >> 4, l15 = lane & 15;
  const int q4x = q4 ^ ((l15 >> 1) & 3);             // swizzled k-slot for LDS reads
  const int swzc = ((tid & 3) ^ ((tid >> 3) & 3)) << 3;  // swizzled staging source col
  const int qt = (int)gridDim.x - 1 - (int)blockIdx.x;  // heavy blocks first
  const int h = blockIdx.y, b = blockIdx.z;
  const int hkv = h >> 2;
  const int qb = qt * 128 + w * 32;
  const int kdiag = qb >> 6;            // wave's diagonal 64-tile
  const int ns = 2 * qt + 2;            // 64-col stages

  const short* Qg = Qb + (size_t)(b * 32 + h) * 65536;
  const short* Kg = Kb + (size_t)(b * 8 + hkv) * 65536;
  const short* Vg = VTb + (size_t)(b * 8 + hkv) * 65536;

  short8 qf[2][2];
#pragma unroll
  for (int mf = 0; mf < 2; ++mf) {
    const short* qr = Qg + (size_t)(qb + mf * 16 + l15) * 64 + q4 * 8;
    qf[mf][0] = *(const short8*)(qr);
    qf[mf][1] = *(const short8*)(qr + 32);
  }

  const f32x4 fz = {0.f, 0.f, 0.f, 0.f};
  f32x4 o[2][4], ol[2];
#pragma unroll
  for (int mf = 0; mf < 2; ++mf) {
    ol[mf] = fz;
#pragma unroll
    for (int i = 0; i < 4; ++i) o[mf][i] = fz;
  }
  short8 ones;
#pragma unroll
  for (int i = 0; i < 8; ++i) ones[i] = (short)0x3F80;

  // per call: wave w writes rows [w*16,+16) of a [64][32] panel (1KB), 4 waves = 4KB
  auto stage = [&](int s, int d) {
    const short* Ksrc = Kg + (size_t)(s * 64 + (tid >> 2)) * 32 + swzc;
    short* kd = (short*)lK + d * 4096 + w * 512;
    gl_lds16(Ksrc, kd);                  // K half0 (d=0..31)
    gl_lds16(Ksrc + 32768, kd + 2048);   // K half1 (d=32..63)
    const short* Vsrc = Vg + (size_t)(2 * s) * 2048 + (tid >> 2) * 32 + swzc;
    short* vd = (short*)lVT + d * 4096 + w * 512;
    gl_lds16(Vsrc, vd);                  // V chunk 2s   (t = s*64..+31)
    gl_lds16(Vsrc + 2048, vd + 2048);    // V chunk 2s+1 (t = s*64+32..+63)
  };

  stage(0, 0);
  for (int s = 0; s < ns; ++s) {
    const int d = s & 1;
    __syncthreads();                     // drains stage(s) loads; all readers done with buf d
    if (s + 1 < ns) stage(s + 1, d ^ 1); // prefetch next stage -- in flight during compute
    if (s <= kdiag) {
      const short* kp = (short*)lK + d * 4096;
      const short* vp = (short*)lVT + d * 4096;
      short8 kf0[4], kf1[4];
#pragma unroll
      for (int nt = 0; nt < 4; ++nt) {
        kf0[nt] = *(const short8*)(kp + (nt * 16 + l15) * 32 + q4x * 8);
        kf1[nt] = *(const short8*)(kp + 2048 + (nt * 16 + l15) * 32 + q4x * 8);
      }
      f32x4 sv[2][4];
#pragma unroll
      for (int mf = 0; mf < 2; ++mf)
#pragma unroll
        for (int nt = 0; nt < 4; ++nt) {
          f32x4 z = __builtin_amdgcn_mfma_f32_16x16x32_bf16(qf[mf][0], kf0[nt], fz, 0, 0, 0);
          sv[mf][nt] = __builtin_amdgcn_mfma_f32_16x16x32_bf16(qf[mf][1], kf1[nt], z, 0, 0, 0);
        }
      if (s == kdiag) {                  // causal mask on the diagonal tile
#pragma unroll
        for (int mf = 0; mf < 2; ++mf)
#pragma unroll
          for (int r = 0; r < 4; ++r) {
            const int qrow = qb + mf * 16 + q4 * 4 + r;
            const int col = s * 64 + l15;
#pragma unroll
            for (int nt = 0; nt < 4; ++nt)
              if (col + nt * 16 > qrow) sv[mf][nt][r] = -1e30f;
          }
      }
      // softmax (fixed-shift, linear state) -> per-wave lP
#pragma unroll
      for (int mf = 0; mf < 2; ++mf) {
        short* lPm = lP[w][mf];
#pragma unroll
        for (int r = 0; r < 4; ++r)
#pragma unroll
          for (int nt = 0; nt < 4; ++nt)
            lPm[(q4 * 4 + r) * PROW + nt * 16 + l15] = f2b(exp2_fast(sv[mf][nt][r] - 16.f));
      }
      short8 vf0[4], vf1[4];
#pragma unroll
      for (int dt = 0; dt < 4; ++dt) {
        vf0[dt] = *(const short8*)(vp + (dt * 16 + l15) * 32 + q4x * 8);
        vf1[dt] = *(const short8*)(vp + 2048 + (dt * 16 + l15) * 32 + q4x * 8);
      }
#pragma unroll
      for (int mf = 0; mf < 2; ++mf) {
        const short* lPm = lP[w][mf];
        short8 pf0 = *(const short8*)(lPm + l15 * PROW + q4 * 8);
        short8 pf1 = *(const short8*)(lPm + l15 * PROW + 32 + q4 * 8);
        ol[mf] = __builtin_amdgcn_mfma_f32_16x16x32_bf16(pf0, ones, ol[mf], 0, 0, 0);
        ol[mf] = __builtin_amdgcn_mfma_f32_16x16x32_bf16(pf1, ones, ol[mf], 0, 0, 0);
#pragma unroll
        for (int dt = 0; dt < 4; ++dt) {
          o[mf][dt] = __builtin_amdgcn_mfma_f32_16x16x32_bf16(pf0, vf0[dt], o[mf][dt], 0, 0, 0);
          o[mf][dt] = __builtin_amdgcn_mfma_f32_16x16x32_bf16(pf1, vf1[dt], o[mf][dt], 0, 0, 0);
        }
      }
    }
  }

#pragma unroll
  for (int mf = 0; mf < 2; ++mf)
#pragma unroll
    for (int r = 0; r < 4; ++r) {
      float inv = __builtin_amdgcn_rcpf(ol[mf][r]);
      int row = qb + mf * 16 + q4 * 4 + r;
#pragma unroll
      for (int dt = 0; dt < 4; ++dt)
        AO[(size_t)(b * 1024 + row) * 2048 + h * 64 + dt * 16 + l15] = f2b(o[mf][dt][r] * inv);
    }
}

// ---------------- output projection: BK=64 double-buffered, fp32 out + bias ----------------
__launch_bounds__(256, 3)
__global__ void gemm_out(const short* __restrict__ A, const short* __restrict__ BT,
                         float* __restrict__ C, const float* __restrict__ bias,
                         int N, int K) {
  __shared__ __align__(16) short lA[16384];
  __shared__ __align__(16) short lB[8192];
  const int tid = threadIdx.x, lane = tid & 63, w = tid >> 6;
  const int q4 = lane >> 4, l15 = lane & 15;
  const int bn = blockIdx.x * 64, bm = blockIdx.y * 128;

  const int swzc = ((tid & 3) ^ ((tid >> 3) & 3)) << 3;
  const short* Ag = A + (size_t)(bm + (tid >> 2)) * K + swzc;
  const short* Bg = BT + (size_t)(bn + (tid >> 2)) * K + swzc;

  f32x4 acc[2][4];
  const f32x4 fz = {0.f, 0.f, 0.f, 0.f};
#pragma unroll
  for (int i = 0; i < 2; ++i)
#pragma unroll
    for (int j = 0; j < 4; ++j) acc[i][j] = fz;

  gemm_loop_bk64(Ag, Bg, lA, lB, w, l15, q4, acc);

#pragma unroll
  for (int mf = 0; mf < 2; ++mf)
#pragma unroll
    for (int nf = 0; nf < 4; ++nf) {
      int col = bn + nf * 16 + l15;
      float bb = bias[col];
#pragma unroll
      for (int r = 0; r < 4; ++r) {
        int row = bm + w * 32 + mf * 16 + q4 * 4 + r;
        C[(size_t)row * N + col] = acc[mf][nf][r] + bb;
      }
    }
}

extern "C" void kernel_launch(void* const* d_in, const int* in_sizes, int n_in,
                              void* d_out, int out_size, void* d_ws, size_t ws_size,
                              hipStream_t stream) {
  const float* x  = (const float*)d_in[0];
  const float* wq = (const float*)d_in[1];
  const float* bq = (const float*)d_in[2];
  const float* wk = (const float*)d_in[3];
  const float* bk = (const float*)d_in[4];
  const float* wv = (const float*)d_in[5];
  const float* bv = (const float*)d_in[6];
  const float* wo = (const float*)d_in[7];
  const float* bo = (const float*)d_in[8];
  float* out = (float*)d_out;
  const int B = in_sizes[0] / (1024 * 2048);
  const int M = B * 1024;

  char* ws = (char*)d_ws;
  size_t off = 0;
  auto alloc = [&](size_t bytes) -> char* {
    char* p = ws + off;
    off += (bytes + 255) & ~(size_t)255;
    return p;
  };
  short* xb    = (short*)alloc((size_t)M * 2048 * 2);
  short* WqkvT = (short*)alloc((size_t)3072 * 2048 * 2);  // rows: wq^T | wk^T | wv^T (K-major)
  short* woT   = (short*)alloc((size_t)2048 * 2048 * 2);
  short* Qb    = (short*)alloc((size_t)B * 32 * 1024 * 64 * 2);    // (b,h,t,d)
  short* Kb    = (short*)alloc((size_t)B * 8 * 2 * 1024 * 32 * 2); // (b,hkv)[dhalf][t][32]
  short* VTb   = (short*)alloc((size_t)B * 8 * 32 * 64 * 32 * 2);  // (b,hkv)[tchunk][d][32]
  short* AO    = (short*)alloc((size_t)M * 2048 * 2);              // (b,t,E) bf16

  cast_x_kernel<<<(M * 2048 / 4 + 255) / 256, 256, 0, stream>>>(x, xb, M * 2048 / 4);
  wtrans_all<<<dim3(80, 32), 256, 0, stream>>>(wq, wk, wv, wo, WqkvT, woT);
  gemm_qkv<<<dim3(48, M / 128), 256, 0, stream>>>(xb, WqkvT, bq, bk, bv, Qb, Kb, VTb);
  attn8_kernel<<<dim3(8, 32, B), 256, 0, stream>>>(Qb, Kb, VTb, AO);
  gemm_out<<<dim3(32, M / 128), 256, 0, stream>>>(AO, woT, out, bo, 2048, 2048);
}

// Round 7
// 196.627 us; speedup vs baseline: 1.0861x; 1.0508x over previous
//
#include <hip/hip_runtime.h>
#include <hip/hip_bf16.h>
#include <cstdint>

// GQA prefill: b=2, t=1024, E=2048, NQ=32, NKV=8, HD=64. fp32 in/out, bf16 MFMA inside.

typedef __attribute__((ext_vector_type(8))) short short8;   // 8 bf16 (MFMA A/B frag)
typedef __attribute__((ext_vector_type(4))) short short4v;
typedef __attribute__((ext_vector_type(4))) float f32x4;    // MFMA C/D frag

__device__ inline short f2b(float f) {  // fp32 -> bf16 (RNE)
  union { float f; unsigned u; } v; v.f = f;
  unsigned r = v.u + 0x7fffu + ((v.u >> 16) & 1u);
  return (short)(r >> 16);
}

__device__ inline float exp2_fast(float x) {
  float r;
  asm("v_exp_f32 %0, %1" : "=v"(r) : "v"(x));
  return r;
}

__device__ inline void gl_lds16(const void* g, void* l) {
  // async global->LDS, 16B/lane; LDS dest = wave-uniform base + lane*16
  __builtin_amdgcn_global_load_lds((const __attribute__((address_space(1))) void*)g,
                                   (__attribute__((address_space(3))) void*)l,
                                   16, 0, 0);
}

// ---------------- fused prep: weight transposes + x cast in one launch ----------------
// grid (80 + ceil(n4/256/32), 32).  bx<80: wtrans jobs (as before); bx>=80: cast x.
__global__ void prep_all(const float* __restrict__ x, const float* __restrict__ wq,
                         const float* __restrict__ wk, const float* __restrict__ wv,
                         const float* __restrict__ wo, short* __restrict__ xb,
                         short* __restrict__ WqkvT, short* __restrict__ woT, int n4) {
  __shared__ float tile[64][65];
  const int bx = blockIdx.x;
  const int tid = threadIdx.x;
  if (bx >= 80) {             // ---- cast x -> bf16 ----
    int i = ((bx - 80) * 32 + blockIdx.y) * 256 + tid;
    if (i < n4) {
      float4 v = ((const float4*)x)[i];
      short4v o; o.x = f2b(v.x); o.y = f2b(v.y); o.z = f2b(v.z); o.w = f2b(v.w);
      ((short4v*)xb)[i] = o;
    }
    return;
  }
  // ---- weight transpose: x<32 wq | <40 wk | <48 wv | else wo. 64x64 tile ----
  const float* W; short* WT; int N, off, nb;
  if (bx < 32)      { W = wq; WT = WqkvT; N = 2048; off = 0;    nb = bx * 64; }
  else if (bx < 40) { W = wk; WT = WqkvT; N = 512;  off = 2048; nb = (bx - 32) * 64; }
  else if (bx < 48) { W = wv; WT = WqkvT; N = 512;  off = 2560; nb = (bx - 40) * 64; }
  else              { W = wo; WT = woT;   N = 2048; off = 0;    nb = (bx - 48) * 64; }
  const int kb = blockIdx.y * 64;
  const int c = tid & 63, r0 = tid >> 6;
#pragma unroll
  for (int s = 0; s < 16; ++s) {
    int k = r0 + s * 4;
    tile[c][k] = W[(size_t)(kb + k) * N + nb + c];
  }
  __syncthreads();
#pragma unroll
  for (int s = 0; s < 16; ++s) {
    int n = r0 + s * 4;
    WT[(size_t)(off + nb + n) * 2048 + kb + c] = f2b(tile[n][c]);
  }
}

// ---------------- shared K-loop: 128(M)x64(N) tile, K=2048, BK=64, double-buffered ----------
// R0 structure (measured best: ~42us for QKV): one __syncthreads per BK=64 stage,
// 32 barriers, per wave per stage 6 gl_lds + 12 ds_read_b128 + 16 MFMA.
// T2 swizzle: LDS linear; GLOBAL source col pre-swizzled (swzc), reads use q4x.
__device__ __forceinline__ void gemm_loop_bk64(const short* __restrict__ Ag,
                                               const short* __restrict__ Bg,
                                               short* lA, short* lB,
                                               int w, int l15, int q4,
                                               f32x4 acc[2][4]) {
  const int K = 2048, NS = 32;  // stages of BK=64
  const int q4x = q4 ^ ((l15 >> 1) & 3);  // swizzled k-slot for LDS reads
  auto stage = [&](int s, int d) {
    const short* As = Ag + s * 64;
    const short* Bs = Bg + s * 64;
    short* a = lA + d * 8192 + w * 512;
    gl_lds16(As, a);                          // panel0 rows [w*16,+16)
    gl_lds16(As + 64 * K, a + 2048);          // panel0 rows +64
    gl_lds16(As + 32, a + 4096);              // panel1 rows [w*16,+16)
    gl_lds16(As + 64 * K + 32, a + 6144);     // panel1 rows +64
    short* bp = lB + d * 4096 + w * 512;
    gl_lds16(Bs, bp);                         // panel0
    gl_lds16(Bs + 32, bp + 2048);             // panel1
  };
  stage(0, 0);
  for (int s = 0; s < NS; ++s) {
    const int d = s & 1;
    __syncthreads();                          // drains stage(s) loads; frees buf d^1
    if (s + 1 < NS) stage(s + 1, d ^ 1);      // prefetch next stage (drained at NEXT barrier)
#pragma unroll
    for (int ks = 0; ks < 2; ++ks) {
      const short* ap = lA + d * 8192 + ks * 4096;
      const short* bp = lB + d * 4096 + ks * 2048;
      short8 af[2], bf[4];
#pragma unroll
      for (int mf = 0; mf < 2; ++mf) af[mf] = *(const short8*)(ap + (w * 32 + mf * 16 + l15) * 32 + q4x * 8);
#pragma unroll
      for (int nf = 0; nf < 4; ++nf) bf[nf] = *(const short8*)(bp + (nf * 16 + l15) * 32 + q4x * 8);
#pragma unroll
      for (int mf = 0; mf < 2; ++mf)
#pragma unroll
        for (int nf = 0; nf < 4; ++nf)
          acc[mf][nf] = __builtin_amdgcn_mfma_f32_16x16x32_bf16(af[mf], bf[nf], acc[mf][nf], 0, 0, 0);
    }
  }
}

// ---------------- fused QKV GEMM + bias + RoPE + scatter epilogue ----------------
// V-epilogue writes the VT panel layout directly (no vtrans kernel).
__launch_bounds__(256, 3)
__global__ void gemm_qkv(const short* __restrict__ A, const short* __restrict__ BT,
                         const float* __restrict__ bq, const float* __restrict__ bk,
                         const float* __restrict__ bv,
                         short* __restrict__ Qb, short* __restrict__ Kb,
                         short* __restrict__ VTb) {
  __shared__ __align__(16) short lA[16384];
  __shared__ __align__(16) short lB[8192];
  const int K = 2048;
  const int tid = threadIdx.x, lane = tid & 63, w = tid >> 6;
  const int q4 = lane >> 4, l15 = lane & 15;
  const int bn = blockIdx.x * 64, bm = blockIdx.y * 128;

  const int swzc = ((tid & 3) ^ ((tid >> 3) & 3)) << 3;
  const short* Ag = A + (size_t)(bm + (tid >> 2)) * K + swzc;
  const short* Bg = BT + (size_t)(bn + (tid >> 2)) * K + swzc;

  f32x4 acc[2][4];
  const f32x4 fz = {0.f, 0.f, 0.f, 0.f};
#pragma unroll
  for (int i = 0; i < 2; ++i)
#pragma unroll
    for (int j = 0; j < 4; ++j) acc[i][j] = fz;

  gemm_loop_bk64(Ag, Bg, lA, lB, w, l15, q4, acc);

  // ----- epilogue -----
  const float L2T = 0.4152410118609203f;          // log2(10000)/32
  const float theta_a = exp2_fast(-(float)l15 * L2T);
  const float theta_b = exp2_fast(-(float)(l15 + 16) * L2T);
  const float s2 = 0.18033688011112042f;          // 0.125 * log2(e): base-2 attn scores

  if (bn < 2048) {            // ---- Q: rope + scale -> Qb (b,h,t,64)
    const int h = bn >> 6;
    float bb0 = bq[bn + l15], bb1 = bq[bn + 16 + l15], bb2 = bq[bn + 32 + l15], bb3 = bq[bn + 48 + l15];
#pragma unroll
    for (int mf = 0; mf < 2; ++mf)
#pragma unroll
      for (int r = 0; r < 4; ++r) {
        int row = bm + w * 32 + mf * 16 + q4 * 4 + r;
        int batch = row >> 10, t = row & 1023;
        float pos = (float)(t + 1);
        float sa, ca, sb, cb;
        __sincosf(pos * theta_a, &sa, &ca);
        __sincosf(pos * theta_b, &sb, &cb);
        float x0 = acc[mf][0][r] + bb0, x2 = acc[mf][2][r] + bb2;
        float x1 = acc[mf][1][r] + bb1, x3 = acc[mf][3][r] + bb3;
        size_t base = ((size_t)(batch * 32 + h) * 1024 + t) * 64;
        Qb[base + l15]      = f2b((x0 * ca - x2 * sa) * s2);
        Qb[base + l15 + 32] = f2b((x2 * ca + x0 * sa) * s2);
        Qb[base + l15 + 16] = f2b((x1 * cb - x3 * sb) * s2);
        Qb[base + l15 + 48] = f2b((x3 * cb + x1 * sb) * s2);
      }
  } else if (bn < 2560) {     // ---- K: rope -> Kb (b,hkv)[dhalf][t][32]
    const int co = bn - 2048;
    const int hkv = co >> 6;
    float bb0 = bk[co + l15], bb1 = bk[co + 16 + l15], bb2 = bk[co + 32 + l15], bb3 = bk[co + 48 + l15];
#pragma unroll
    for (int mf = 0; mf < 2; ++mf)
#pragma unroll
      for (int r = 0; r < 4; ++r) {
        int row = bm + w * 32 + mf * 16 + q4 * 4 + r;
        int batch = row >> 10, t = row & 1023;
        float pos = (float)(t + 1);
        float sa, ca, sb, cb;
        __sincosf(pos * theta_a, &sa, &ca);
        __sincosf(pos * theta_b, &sb, &cb);
        float x0 = acc[mf][0][r] + bb0, x2 = acc[mf][2][r] + bb2;
        float x1 = acc[mf][1][r] + bb1, x3 = acc[mf][3][r] + bb3;
        size_t base = (size_t)(batch * 8 + hkv) * 65536 + t * 32;
        Kb[base + l15]              = f2b(x0 * ca - x2 * sa);  // d=l15      (half0)
        Kb[base + l15 + 16]         = f2b(x1 * cb - x3 * sb);  // d=l15+16   (half0)
        Kb[base + 32768 + l15]      = f2b(x2 * ca + x0 * sa);  // d=l15+32   (half1)
        Kb[base + 32768 + l15 + 16] = f2b(x3 * cb + x1 * sb);  // d=l15+48   (half1)
      }
  } else {                    // ---- V: bias -> VTb (b,hkv)[tchunk32][d64][32] directly
    const int co = bn - 2560;
    const int hkv = co >> 6;
    float bb[4];
#pragma unroll
    for (int nf = 0; nf < 4; ++nf) bb[nf] = bv[co + nf * 16 + l15];
    const int batch = (bm + w * 32) >> 10;          // bm%128==0, w*32<128: no crossing
    const size_t vbase = (size_t)(batch * 8 + hkv) * 65536;
#pragma unroll
    for (int mf = 0; mf < 2; ++mf) {
      const int t0 = (bm + w * 32 + mf * 16 + q4 * 4) & 1023;
      const size_t rbase = vbase + (size_t)(t0 >> 5) * 2048 + (t0 & 31);
#pragma unroll
      for (int nf = 0; nf < 4; ++nf) {
        short4v pk;
#pragma unroll
        for (int r = 0; r < 4; ++r) pk[r] = f2b(acc[mf][nf][r] + bb[nf]);
        *(short4v*)(VTb + rbase + (nf * 16 + l15) * 32) = pk;
      }
    }
  }
}

// ---------------- flash attention v9: causal PAIR tiling -- uniform-work blocks ----------------
// q-tiles of 64 rows (16/batch-head).  Block bx handles the pair {bx, 15-bx}:
// (bx+1) + (16-bx) = 17 stages of 64 k-cols for EVERY block -- zero work skew
// (R6 diagnosis: 13% occupancy from 8:1 causal imbalance, not staging latency).
// grid (8, 32, B) = 512 uniform blocks; 4 waves; wave w owns q-rows [j*64+w*16,+16).
// K/V staged in LDS (shared by 4 waves), double-buffered with prefetch-before-
// compute; same fixed-shift softmax + lP path + T2 swizzle as attn5/8.
#define PROW 72
__launch_bounds__(256, 3)
__global__ void attn9_kernel(const short* __restrict__ Qb, const short* __restrict__ Kb,
                             const short* __restrict__ VTb, short* __restrict__ AO) {
  __shared__ __align__(16) short lK[2 * 4096];     // [dbuf][dhalf][krow64][32]  16KB
  __shared__ __align__(16) short lVT[2 * 4096];    // [dbuf][tchunk][d64][32]    16KB
  __shared__ __align__(16) short lP[4][16 * PROW]; // per-wave P (16 q-rows)      9KB
  const int tid = threadIdx.x, lane = tid & 63, w = tid >> 6;
  const int q4 = lane >> 4, l15 = lane & 15;
  const int q4x = q4 ^ ((l15 >> 1) & 3);
  const int swzc = ((tid & 3) ^ ((tid >> 3) & 3)) << 3;
  const int pr = blockIdx.x;            // pair index 0..7
  const int jA = pr, jB = 15 - pr;      // the two 64-row q-tiles
  const int h = blockIdx.y, b = blockIdx.z;
  const int hkv = h >> 2;

  const short* Qg = Qb + (size_t)(b * 32 + h) * 65536;
  const short* Kg = Kb + (size_t)(b * 8 + hkv) * 65536;
  const short* Vg = VTb + (size_t)(b * 8 + hkv) * 65536;

  short8 qfA0, qfA1, qfB0, qfB1;
  {
    const short* qr = Qg + (size_t)(jA * 64 + w * 16 + l15) * 64 + q4 * 8;
    qfA0 = *(const short8*)(qr); qfA1 = *(const short8*)(qr + 32);
    const short* qr2 = Qg + (size_t)(jB * 64 + w * 16 + l15) * 64 + q4 * 8;
    qfB0 = *(const short8*)(qr2); qfB1 = *(const short8*)(qr2 + 32);
  }

  const f32x4 fz = {0.f, 0.f, 0.f, 0.f};
  f32x4 o[4], ol;
  short8 ones;
#pragma unroll
  for (int i = 0; i < 8; ++i) ones[i] = (short)0x3F80;

  // stage k-tile kt (64 cols of K + V) into buffer d: 4 gl_lds16 per wave
  auto stage = [&](int kt, int d) {
    const short* Ksrc = Kg + (size_t)(kt * 64 + (tid >> 2)) * 32 + swzc;
    short* kd = lK + d * 4096 + w * 512;
    gl_lds16(Ksrc, kd);                  // K half0 (d=0..31), rows [w*16,+16)
    gl_lds16(Ksrc + 32768, kd + 2048);   // K half1 (d=32..63)
    const short* Vsrc = Vg + (size_t)(2 * kt) * 2048 + (tid >> 2) * 32 + swzc;
    short* vd = lVT + d * 4096 + w * 512;
    gl_lds16(Vsrc, vd);                  // V chunk 2kt   (t = kt*64..+31)
    gl_lds16(Vsrc + 2048, vd + 2048);    // V chunk 2kt+1 (t = kt*64+32..+63)
  };

  // one 64x64 score tile + PV for q-tile jt, k-tile kt, from buffer d
  auto comp = [&](int d, int kt, int jt, short8 qf0, short8 qf1) {
    const short* kp = lK + d * 4096;
    const short* vp = lVT + d * 4096;
    short8 kf0[4], kf1[4];
#pragma unroll
    for (int nt = 0; nt < 4; ++nt) {
      kf0[nt] = *(const short8*)(kp + (nt * 16 + l15) * 32 + q4x * 8);
      kf1[nt] = *(const short8*)(kp + 2048 + (nt * 16 + l15) * 32 + q4x * 8);
    }
    f32x4 sv[4];
#pragma unroll
    for (int nt = 0; nt < 4; ++nt) {
      f32x4 z = __builtin_amdgcn_mfma_f32_16x16x32_bf16(qf0, kf0[nt], fz, 0, 0, 0);
      sv[nt] = __builtin_amdgcn_mfma_f32_16x16x32_bf16(qf1, kf1[nt], z, 0, 0, 0);
    }
    if (kt == jt) {                      // diagonal tile: causal mask
#pragma unroll
      for (int r = 0; r < 4; ++r) {
        const int qrow = jt * 64 + w * 16 + q4 * 4 + r;
        const int col = kt * 64 + l15;
#pragma unroll
        for (int nt = 0; nt < 4; ++nt)
          if (col + nt * 16 > qrow) sv[nt][r] = -1e30f;
      }
    }
    short* lPm = lP[w];
#pragma unroll
    for (int r = 0; r < 4; ++r)
#pragma unroll
      for (int nt = 0; nt < 4; ++nt)
        lPm[(q4 * 4 + r) * PROW + nt * 16 + l15] = f2b(exp2_fast(sv[nt][r] - 16.f));
    short8 vf0[4], vf1[4];
#pragma unroll
    for (int dt = 0; dt < 4; ++dt) {
      vf0[dt] = *(const short8*)(vp + (dt * 16 + l15) * 32 + q4x * 8);
      vf1[dt] = *(const short8*)(vp + 2048 + (dt * 16 + l15) * 32 + q4x * 8);
    }
    short8 pf0 = *(const short8*)(lPm + l15 * PROW + q4 * 8);
    short8 pf1 = *(const short8*)(lPm + l15 * PROW + 32 + q4 * 8);
    ol = __builtin_amdgcn_mfma_f32_16x16x32_bf16(pf0, ones, ol, 0, 0, 0);
    ol = __builtin_amdgcn_mfma_f32_16x16x32_bf16(pf1, ones, ol, 0, 0, 0);
#pragma unroll
    for (int dt = 0; dt < 4; ++dt) {
      o[dt] = __builtin_amdgcn_mfma_f32_16x16x32_bf16(pf0, vf0[dt], o[dt], 0, 0, 0);
      o[dt] = __builtin_amdgcn_mfma_f32_16x16x32_bf16(pf1, vf1[dt], o[dt], 0, 0, 0);
    }
  };

  auto emit = [&](int jt) {
#pragma unroll
    for (int r = 0; r < 4; ++r) {
      float inv = __builtin_amdgcn_rcpf(ol[r]);
      int row = jt * 64 + w * 16 + q4 * 4 + r;
#pragma unroll
      for (int dt = 0; dt < 4; ++dt)
        AO[(size_t)(b * 1024 + row) * 2048 + h * 64 + dt * 16 + l15] = f2b(o[dt][r] * inv);
    }
  };

  ol = fz;
#pragma unroll
  for (int dt = 0; dt < 4; ++dt) o[dt] = fz;

  const int nsA = jA + 1;                // stages for tile A; total = 17 always
  stage(0, 0);
  for (int s = 0; s < 17; ++s) {
    const int d = s & 1;
    __syncthreads();                     // drains stage(s); all readers done with buf d
    if (s + 1 < 17) stage((s + 1 < nsA) ? s + 1 : s + 1 - nsA, d ^ 1);
    if (s < nsA) {
      comp(d, s, jA, qfA0, qfA1);
    } else {
      if (s == nsA) {                    // tile A done: write it out, reset acc
        emit(jA);
        ol = fz;
#pragma unroll
        for (int dt = 0; dt < 4; ++dt) o[dt] = fz;
      }
      comp(d, s - nsA, jB, qfB0, qfB1);
    }
  }
  emit(jB);
}

// ---------------- output projection: BK=64 double-buffered, fp32 out + bias ----------------
__launch_bounds__(256, 3)
__global__ void gemm_out(const short* __restrict__ A, const short* __restrict__ BT,
                         float* __restrict__ C, const float* __restrict__ bias,
                         int N, int K) {
  __shared__ __align__(16) short lA[16384];
  __shared__ __align__(16) short lB[8192];
  const int tid = threadIdx.x, lane = tid & 63, w = tid >> 6;
  const int q4 = lane >> 4, l15 = lane & 15;
  const int bn = blockIdx.x * 64, bm = blockIdx.y * 128;

  const int swzc = ((tid & 3) ^ ((tid >> 3) & 3)) << 3;
  const short* Ag = A + (size_t)(bm + (tid >> 2)) * K + swzc;
  const short* Bg = BT + (size_t)(bn + (tid >> 2)) * K + swzc;

  f32x4 acc[2][4];
  const f32x4 fz = {0.f, 0.f, 0.f, 0.f};
#pragma unroll
  for (int i = 0; i < 2; ++i)
#pragma unroll
    for (int j = 0; j < 4; ++j) acc[i][j] = fz;

  gemm_loop_bk64(Ag, Bg, lA, lB, w, l15, q4, acc);

#pragma unroll
  for (int mf = 0; mf < 2; ++mf)
#pragma unroll
    for (int nf = 0; nf < 4; ++nf) {
      int col = bn + nf * 16 + l15;
      float bb = bias[col];
#pragma unroll
      for (int r = 0; r < 4; ++r) {
        int row = bm + w * 32 + mf * 16 + q4 * 4 + r;
        C[(size_t)row * N + col] = acc[mf][nf][r] + bb;
      }
    }
}

extern "C" void kernel_launch(void* const* d_in, const int* in_sizes, int n_in,
                              void* d_out, int out_size, void* d_ws, size_t ws_size,
                              hipStream_t stream) {
  const float* x  = (const float*)d_in[0];
  const float* wq = (const float*)d_in[1];
  const float* bq = (const float*)d_in[2];
  const float* wk = (const float*)d_in[3];
  const float* bk = (const float*)d_in[4];
  const float* wv = (const float*)d_in[5];
  const float* bv = (const float*)d_in[6];
  const float* wo = (const float*)d_in[7];
  const float* bo = (const float*)d_in[8];
  float* out = (float*)d_out;
  const int B = in_sizes[0] / (1024 * 2048);
  const int M = B * 1024;

  char* ws = (char*)d_ws;
  size_t off = 0;
  auto alloc = [&](size_t bytes) -> char* {
    char* p = ws + off;
    off += (bytes + 255) & ~(size_t)255;
    return p;
  };
  short* xb    = (short*)alloc((size_t)M * 2048 * 2);
  short* WqkvT = (short*)alloc((size_t)3072 * 2048 * 2);  // rows: wq^T | wk^T | wv^T (K-major)
  short* woT   = (short*)alloc((size_t)2048 * 2048 * 2);
  short* Qb    = (short*)alloc((size_t)B * 32 * 1024 * 64 * 2);    // (b,h,t,d)
  short* Kb    = (short*)alloc((size_t)B * 8 * 2 * 1024 * 32 * 2); // (b,hkv)[dhalf][t][32]
  short* VTb   = (short*)alloc((size_t)B * 8 * 32 * 64 * 32 * 2);  // (b,hkv)[tchunk][d][32]
  short* AO    = (short*)alloc((size_t)M * 2048 * 2);              // (b,t,E) bf16

  const int n4 = M * 2048 / 4;
  const int nbc = (n4 + 255) / 256;
  prep_all<<<dim3(80 + (nbc + 31) / 32, 32), 256, 0, stream>>>(x, wq, wk, wv, wo, xb, WqkvT, woT, n4);
  gemm_qkv<<<dim3(48, M / 128), 256, 0, stream>>>(xb, WqkvT, bq, bk, bv, Qb, Kb, VTb);
  attn9_kernel<<<dim3(8, 32, B), 256, 0, stream>>>(Qb, Kb, VTb, AO);
  gemm_out<<<dim3(32, M / 128), 256, 0, stream>>>(AO, woT, out, bo, 2048, 2048);
}

// Round 8
// 196.282 us; speedup vs baseline: 1.0880x; 1.0018x over previous
//
#include <hip/hip_runtime.h>
#include <hip/hip_bf16.h>
#include <cstdint>

// GQA prefill: b=2, t=1024, E=2048, NQ=32, NKV=8, HD=64. fp32 in/out, bf16 MFMA inside.

typedef __attribute__((ext_vector_type(8))) short short8;   // 8 bf16 (MFMA A/B frag)
typedef __attribute__((ext_vector_type(4))) short short4v;
typedef __attribute__((ext_vector_type(4))) float f32x4;    // MFMA C/D frag

__device__ inline short f2b(float f) {  // fp32 -> bf16 (RNE)
  union { float f; unsigned u; } v; v.f = f;
  unsigned r = v.u + 0x7fffu + ((v.u >> 16) & 1u);
  return (short)(r >> 16);
}

__device__ inline float exp2_fast(float x) {
  float r;
  asm("v_exp_f32 %0, %1" : "=v"(r) : "v"(x));
  return r;
}

__device__ inline void gl_lds16(const void* g, void* l) {
  // async global->LDS, 16B/lane; LDS dest = wave-uniform base + lane*16
  __builtin_amdgcn_global_load_lds((const __attribute__((address_space(1))) void*)g,
                                   (__attribute__((address_space(3))) void*)l,
                                   16, 0, 0);
}

// ---------------- fused prep: weight transposes + x cast in one launch ----------------
// grid (80 + ceil(n4/256/32), 32).  bx<80: wtrans jobs; bx>=80: cast x.
__global__ void prep_all(const float* __restrict__ x, const float* __restrict__ wq,
                         const float* __restrict__ wk, const float* __restrict__ wv,
                         const float* __restrict__ wo, short* __restrict__ xb,
                         short* __restrict__ WqkvT, short* __restrict__ woT, int n4) {
  __shared__ float tile[64][65];
  const int bx = blockIdx.x;
  const int tid = threadIdx.x;
  if (bx >= 80) {             // ---- cast x -> bf16 ----
    int i = ((bx - 80) * 32 + blockIdx.y) * 256 + tid;
    if (i < n4) {
      float4 v = ((const float4*)x)[i];
      short4v o; o.x = f2b(v.x); o.y = f2b(v.y); o.z = f2b(v.z); o.w = f2b(v.w);
      ((short4v*)xb)[i] = o;
    }
    return;
  }
  // ---- weight transpose: x<32 wq | <40 wk | <48 wv | else wo. 64x64 tile ----
  const float* W; short* WT; int N, off, nb;
  if (bx < 32)      { W = wq; WT = WqkvT; N = 2048; off = 0;    nb = bx * 64; }
  else if (bx < 40) { W = wk; WT = WqkvT; N = 512;  off = 2048; nb = (bx - 32) * 64; }
  else if (bx < 48) { W = wv; WT = WqkvT; N = 512;  off = 2560; nb = (bx - 40) * 64; }
  else              { W = wo; WT = woT;   N = 2048; off = 0;    nb = (bx - 48) * 64; }
  const int kb = blockIdx.y * 64;
  const int c = tid & 63, r0 = tid >> 6;
#pragma unroll
  for (int s = 0; s < 16; ++s) {
    int k = r0 + s * 4;
    tile[c][k] = W[(size_t)(kb + k) * N + nb + c];
  }
  __syncthreads();
#pragma unroll
  for (int s = 0; s < 16; ++s) {
    int n = r0 + s * 4;
    WT[(size_t)(off + nb + n) * 2048 + kb + c] = f2b(tile[n][c]);
  }
}

// ---------------- shared K-loop: 128(M)x64(N) tile, K=2048, BK=64, double-buffered ----------
// R0 structure (measured best: ~42us for QKV): one __syncthreads per BK=64 stage,
// 32 barriers, per wave per stage 6 gl_lds + 12 ds_read_b128 + 16 MFMA.
// T2 swizzle: LDS linear; GLOBAL source col pre-swizzled (swzc), reads use q4x.
__device__ __forceinline__ void gemm_loop_bk64(const short* __restrict__ Ag,
                                               const short* __restrict__ Bg,
                                               short* lA, short* lB,
                                               int w, int l15, int q4,
                                               f32x4 acc[2][4]) {
  const int K = 2048, NS = 32;  // stages of BK=64
  const int q4x = q4 ^ ((l15 >> 1) & 3);  // swizzled k-slot for LDS reads
  auto stage = [&](int s, int d) {
    const short* As = Ag + s * 64;
    const short* Bs = Bg + s * 64;
    short* a = lA + d * 8192 + w * 512;
    gl_lds16(As, a);                          // panel0 rows [w*16,+16)
    gl_lds16(As + 64 * K, a + 2048);          // panel0 rows +64
    gl_lds16(As + 32, a + 4096);              // panel1 rows [w*16,+16)
    gl_lds16(As + 64 * K + 32, a + 6144);     // panel1 rows +64
    short* bp = lB + d * 4096 + w * 512;
    gl_lds16(Bs, bp);                         // panel0
    gl_lds16(Bs + 32, bp + 2048);             // panel1
  };
  stage(0, 0);
  for (int s = 0; s < NS; ++s) {
    const int d = s & 1;
    __syncthreads();                          // drains stage(s) loads; frees buf d^1
    if (s + 1 < NS) stage(s + 1, d ^ 1);      // prefetch next stage (drained at NEXT barrier)
#pragma unroll
    for (int ks = 0; ks < 2; ++ks) {
      const short* ap = lA + d * 8192 + ks * 4096;
      const short* bp = lB + d * 4096 + ks * 2048;
      short8 af[2], bf[4];
#pragma unroll
      for (int mf = 0; mf < 2; ++mf) af[mf] = *(const short8*)(ap + (w * 32 + mf * 16 + l15) * 32 + q4x * 8);
#pragma unroll
      for (int nf = 0; nf < 4; ++nf) bf[nf] = *(const short8*)(bp + (nf * 16 + l15) * 32 + q4x * 8);
#pragma unroll
      for (int mf = 0; mf < 2; ++mf)
#pragma unroll
        for (int nf = 0; nf < 4; ++nf)
          acc[mf][nf] = __builtin_amdgcn_mfma_f32_16x16x32_bf16(af[mf], bf[nf], acc[mf][nf], 0, 0, 0);
    }
  }
}

// ---------------- fused QKV GEMM + bias + RoPE + scatter epilogue ----------------
// V-epilogue writes the VT panel layout directly (no vtrans kernel).
__launch_bounds__(256, 3)
__global__ void gemm_qkv(const short* __restrict__ A, const short* __restrict__ BT,
                         const float* __restrict__ bq, const float* __restrict__ bk,
                         const float* __restrict__ bv,
                         short* __restrict__ Qb, short* __restrict__ Kb,
                         short* __restrict__ VTb) {
  __shared__ __align__(16) short lA[16384];
  __shared__ __align__(16) short lB[8192];
  const int K = 2048;
  const int tid = threadIdx.x, lane = tid & 63, w = tid >> 6;
  const int q4 = lane >> 4, l15 = lane & 15;
  const int bn = blockIdx.x * 64, bm = blockIdx.y * 128;

  const int swzc = ((tid & 3) ^ ((tid >> 3) & 3)) << 3;
  const short* Ag = A + (size_t)(bm + (tid >> 2)) * K + swzc;
  const short* Bg = BT + (size_t)(bn + (tid >> 2)) * K + swzc;

  f32x4 acc[2][4];
  const f32x4 fz = {0.f, 0.f, 0.f, 0.f};
#pragma unroll
  for (int i = 0; i < 2; ++i)
#pragma unroll
    for (int j = 0; j < 4; ++j) acc[i][j] = fz;

  gemm_loop_bk64(Ag, Bg, lA, lB, w, l15, q4, acc);

  // ----- epilogue -----
  const float L2T = 0.4152410118609203f;          // log2(10000)/32
  const float theta_a = exp2_fast(-(float)l15 * L2T);
  const float theta_b = exp2_fast(-(float)(l15 + 16) * L2T);
  const float s2 = 0.18033688011112042f;          // 0.125 * log2(e): base-2 attn scores

  if (bn < 2048) {            // ---- Q: rope + scale -> Qb (b,h,t,64)
    const int h = bn >> 6;
    float bb0 = bq[bn + l15], bb1 = bq[bn + 16 + l15], bb2 = bq[bn + 32 + l15], bb3 = bq[bn + 48 + l15];
#pragma unroll
    for (int mf = 0; mf < 2; ++mf)
#pragma unroll
      for (int r = 0; r < 4; ++r) {
        int row = bm + w * 32 + mf * 16 + q4 * 4 + r;
        int batch = row >> 10, t = row & 1023;
        float pos = (float)(t + 1);
        float sa, ca, sb, cb;
        __sincosf(pos * theta_a, &sa, &ca);
        __sincosf(pos * theta_b, &sb, &cb);
        float x0 = acc[mf][0][r] + bb0, x2 = acc[mf][2][r] + bb2;
        float x1 = acc[mf][1][r] + bb1, x3 = acc[mf][3][r] + bb3;
        size_t base = ((size_t)(batch * 32 + h) * 1024 + t) * 64;
        Qb[base + l15]      = f2b((x0 * ca - x2 * sa) * s2);
        Qb[base + l15 + 32] = f2b((x2 * ca + x0 * sa) * s2);
        Qb[base + l15 + 16] = f2b((x1 * cb - x3 * sb) * s2);
        Qb[base + l15 + 48] = f2b((x3 * cb + x1 * sb) * s2);
      }
  } else if (bn < 2560) {     // ---- K: rope -> Kb (b,hkv)[dhalf][t][32]
    const int co = bn - 2048;
    const int hkv = co >> 6;
    float bb0 = bk[co + l15], bb1 = bk[co + 16 + l15], bb2 = bk[co + 32 + l15], bb3 = bk[co + 48 + l15];
#pragma unroll
    for (int mf = 0; mf < 2; ++mf)
#pragma unroll
      for (int r = 0; r < 4; ++r) {
        int row = bm + w * 32 + mf * 16 + q4 * 4 + r;
        int batch = row >> 10, t = row & 1023;
        float pos = (float)(t + 1);
        float sa, ca, sb, cb;
        __sincosf(pos * theta_a, &sa, &ca);
        __sincosf(pos * theta_b, &sb, &cb);
        float x0 = acc[mf][0][r] + bb0, x2 = acc[mf][2][r] + bb2;
        float x1 = acc[mf][1][r] + bb1, x3 = acc[mf][3][r] + bb3;
        size_t base = (size_t)(batch * 8 + hkv) * 65536 + t * 32;
        Kb[base + l15]              = f2b(x0 * ca - x2 * sa);  // d=l15      (half0)
        Kb[base + l15 + 16]         = f2b(x1 * cb - x3 * sb);  // d=l15+16   (half0)
        Kb[base + 32768 + l15]      = f2b(x2 * ca + x0 * sa);  // d=l15+32   (half1)
        Kb[base + 32768 + l15 + 16] = f2b(x3 * cb + x1 * sb);  // d=l15+48   (half1)
      }
  } else {                    // ---- V: bias -> VTb (b,hkv)[tchunk32][d64][32] directly
    const int co = bn - 2560;
    const int hkv = co >> 6;
    float bb[4];
#pragma unroll
    for (int nf = 0; nf < 4; ++nf) bb[nf] = bv[co + nf * 16 + l15];
    const int batch = (bm + w * 32) >> 10;          // bm%128==0, w*32<128: no crossing
    const size_t vbase = (size_t)(batch * 8 + hkv) * 65536;
#pragma unroll
    for (int mf = 0; mf < 2; ++mf) {
      const int t0 = (bm + w * 32 + mf * 16 + q4 * 4) & 1023;
      const size_t rbase = vbase + (size_t)(t0 >> 5) * 2048 + (t0 & 31);
#pragma unroll
      for (int nf = 0; nf < 4; ++nf) {
        short4v pk;
#pragma unroll
        for (int r = 0; r < 4; ++r) pk[r] = f2b(acc[mf][nf][r] + bb[nf]);
        *(short4v*)(VTb + rbase + (nf * 16 + l15) * 32) = pk;
      }
    }
  }
}

// ---------------- flash attention v10: pair tiling + QK/PV software pipeline ----------------
// attn9 (uniform-work pair blocks, R7 win) + cross-stage pipeline: PV(s-1) runs in
// iteration s, so the serial exp -> lP-write -> lgkm -> lP-read -> PV chain is gone:
// PV consumes P/V written a full stage earlier (latency long since covered), and
// QK(s)/PV(s-1) ops interleave freely (no data deps).
// Buffers: K 2-deep (read at QK), V 3-deep (read 1 stage later), lP 2-deep (parity).
// Race check: buffer overwritten by stage(s+1) was last read >=1 barrier earlier.
// grid (8, 32, B) = 512 uniform blocks (17 stages each); 4 waves, 16 q-rows/wave.
#define PROW 72
__launch_bounds__(256, 2)
__global__ void attn10_kernel(const short* __restrict__ Qb, const short* __restrict__ Kb,
                              const short* __restrict__ VTb, short* __restrict__ AO) {
  __shared__ __align__(16) short lK[2 * 4096];        // [kbuf2][dhalf][krow64][32] 16KB
  __shared__ __align__(16) short lV[3 * 4096];        // [vbuf3][tchunk2][d64][32]  24KB
  __shared__ __align__(16) short lP[2][4][16 * PROW]; // [parity][wave]             18KB
  const int tid = threadIdx.x, lane = tid & 63, w = tid >> 6;
  const int q4 = lane >> 4, l15 = lane & 15;
  const int q4x = q4 ^ ((l15 >> 1) & 3);
  const int swzc = ((tid & 3) ^ ((tid >> 3) & 3)) << 3;
  const int pr = blockIdx.x;            // pair index 0..7
  const int jA = pr, jB = 15 - pr;      // the two 64-row q-tiles
  const int nsA = jA + 1;               // stages for tile A; total = 17 always
  const int h = blockIdx.y, b = blockIdx.z;
  const int hkv = h >> 2;

  const short* Qg = Qb + (size_t)(b * 32 + h) * 65536;
  const short* Kg = Kb + (size_t)(b * 8 + hkv) * 65536;
  const short* Vg = VTb + (size_t)(b * 8 + hkv) * 65536;

  short8 qfA0, qfA1, qfB0, qfB1;
  {
    const short* qr = Qg + (size_t)(jA * 64 + w * 16 + l15) * 64 + q4 * 8;
    qfA0 = *(const short8*)(qr); qfA1 = *(const short8*)(qr + 32);
    const short* qr2 = Qg + (size_t)(jB * 64 + w * 16 + l15) * 64 + q4 * 8;
    qfB0 = *(const short8*)(qr2); qfB1 = *(const short8*)(qr2 + 32);
  }

  const f32x4 fz = {0.f, 0.f, 0.f, 0.f};
  f32x4 o[4], ol;
  short8 ones;
#pragma unroll
  for (int i = 0; i < 8; ++i) ones[i] = (short)0x3F80;
  ol = fz;
#pragma unroll
  for (int dt = 0; dt < 4; ++dt) o[dt] = fz;

  // stage s: K -> kbuf[s&1], V -> vbuf[s%3]; 4 gl_lds16 per wave
  auto stage = [&](int s) {
    const int kt = (s < nsA) ? s : s - nsA;
    const short* Ksrc = Kg + (size_t)(kt * 64 + (tid >> 2)) * 32 + swzc;
    short* kd = lK + (s & 1) * 4096 + w * 512;
    gl_lds16(Ksrc, kd);                  // K half0 (d=0..31), rows [w*16,+16)
    gl_lds16(Ksrc + 32768, kd + 2048);   // K half1 (d=32..63)
    const short* Vsrc = Vg + (size_t)(2 * kt) * 2048 + (tid >> 2) * 32 + swzc;
    short* vd = lV + (s % 3) * 4096 + w * 512;
    gl_lds16(Vsrc, vd);                  // V chunk 2kt
    gl_lds16(Vsrc + 2048, vd + 2048);    // V chunk 2kt+1
  };

  // QK phase for stage s: scores -> exp -> lP[s&1][w]
  auto qk = [&](int s) {
    const int inA = (s < nsA);
    const int jt = inA ? jA : jB;
    const int kt = inA ? s : s - nsA;
    const short8 qf0 = inA ? qfA0 : qfB0;
    const short8 qf1 = inA ? qfA1 : qfB1;
    const short* kp = lK + (s & 1) * 4096;
    short8 kf0[4], kf1[4];
#pragma unroll
    for (int nt = 0; nt < 4; ++nt) {
      kf0[nt] = *(const short8*)(kp + (nt * 16 + l15) * 32 + q4x * 8);
      kf1[nt] = *(const short8*)(kp + 2048 + (nt * 16 + l15) * 32 + q4x * 8);
    }
    f32x4 sv[4];
#pragma unroll
    for (int nt = 0; nt < 4; ++nt) {
      f32x4 z = __builtin_amdgcn_mfma_f32_16x16x32_bf16(qf0, kf0[nt], fz, 0, 0, 0);
      sv[nt] = __builtin_amdgcn_mfma_f32_16x16x32_bf16(qf1, kf1[nt], z, 0, 0, 0);
    }
    if (kt == jt) {                      // diagonal tile: causal mask
#pragma unroll
      for (int r = 0; r < 4; ++r) {
        const int qrow = jt * 64 + w * 16 + q4 * 4 + r;
        const int col = kt * 64 + l15;
#pragma unroll
        for (int nt = 0; nt < 4; ++nt)
          if (col + nt * 16 > qrow) sv[nt][r] = -1e30f;
      }
    }
    short* lPm = lP[s & 1][w];
#pragma unroll
    for (int r = 0; r < 4; ++r)
#pragma unroll
      for (int nt = 0; nt < 4; ++nt)
        lPm[(q4 * 4 + r) * PROW + nt * 16 + l15] = f2b(exp2_fast(sv[nt][r] - 16.f));
  };

  // PV phase for stage sp (P and V one stage old -> no in-iteration dependency)
  auto pv = [&](int sp) {
    const short* vp = lV + (sp % 3) * 4096;
    const short* lPm = lP[sp & 1][w];
    short8 vf0[4], vf1[4];
#pragma unroll
    for (int dt = 0; dt < 4; ++dt) {
      vf0[dt] = *(const short8*)(vp + (dt * 16 + l15) * 32 + q4x * 8);
      vf1[dt] = *(const short8*)(vp + 2048 + (dt * 16 + l15) * 32 + q4x * 8);
    }
    short8 pf0 = *(const short8*)(lPm + l15 * PROW + q4 * 8);
    short8 pf1 = *(const short8*)(lPm + l15 * PROW + 32 + q4 * 8);
    ol = __builtin_amdgcn_mfma_f32_16x16x32_bf16(pf0, ones, ol, 0, 0, 0);
    ol = __builtin_amdgcn_mfma_f32_16x16x32_bf16(pf1, ones, ol, 0, 0, 0);
#pragma unroll
    for (int dt = 0; dt < 4; ++dt) {
      o[dt] = __builtin_amdgcn_mfma_f32_16x16x32_bf16(pf0, vf0[dt], o[dt], 0, 0, 0);
      o[dt] = __builtin_amdgcn_mfma_f32_16x16x32_bf16(pf1, vf1[dt], o[dt], 0, 0, 0);
    }
  };

  auto emit = [&](int jt) {
#pragma unroll
    for (int r = 0; r < 4; ++r) {
      float inv = __builtin_amdgcn_rcpf(ol[r]);
      int row = jt * 64 + w * 16 + q4 * 4 + r;
#pragma unroll
      for (int dt = 0; dt < 4; ++dt)
        AO[(size_t)(b * 1024 + row) * 2048 + h * 64 + dt * 16 + l15] = f2b(o[dt][r] * inv);
    }
  };

  stage(0);
  for (int s = 0; s < 17; ++s) {
    __syncthreads();                     // stage(s) landed; PV(s-2)/QK(s-1) readers done
    if (s + 1 < 17) stage(s + 1);        // prefetch: K->kbuf[(s+1)&1], V->vbuf[(s+1)%3]
    qk(s);                               // produce P(s) into lP[s&1]
    if (s > 0) {
      pv(s - 1);                         // consume P(s-1), V(s-1): stage-old, dep-free
      if (s - 1 == nsA - 1) {            // tile A complete: write + reset accumulators
        emit(jA);
        ol = fz;
#pragma unroll
        for (int dt = 0; dt < 4; ++dt) o[dt] = fz;
      }
    }
  }
  pv(16);                                // drain the last pending PV (tile B diag)
  emit(jB);
}

// ---------------- output projection: BK=64 double-buffered, fp32 out + bias ----------------
__launch_bounds__(256, 3)
__global__ void gemm_out(const short* __restrict__ A, const short* __restrict__ BT,
                         float* __restrict__ C, const float* __restrict__ bias,
                         int N, int K) {
  __shared__ __align__(16) short lA[16384];
  __shared__ __align__(16) short lB[8192];
  const int tid = threadIdx.x, lane = tid & 63, w = tid >> 6;
  const int q4 = lane >> 4, l15 = lane & 15;
  const int bn = blockIdx.x * 64, bm = blockIdx.y * 128;

  const int swzc = ((tid & 3) ^ ((tid >> 3) & 3)) << 3;
  const short* Ag = A + (size_t)(bm + (tid >> 2)) * K + swzc;
  const short* Bg = BT + (size_t)(bn + (tid >> 2)) * K + swzc;

  f32x4 acc[2][4];
  const f32x4 fz = {0.f, 0.f, 0.f, 0.f};
#pragma unroll
  for (int i = 0; i < 2; ++i)
#pragma unroll
    for (int j = 0; j < 4; ++j) acc[i][j] = fz;

  gemm_loop_bk64(Ag, Bg, lA, lB, w, l15, q4, acc);

#pragma unroll
  for (int mf = 0; mf < 2; ++mf)
#pragma unroll
    for (int nf = 0; nf < 4; ++nf) {
      int col = bn + nf * 16 + l15;
      float bb = bias[col];
#pragma unroll
      for (int r = 0; r < 4; ++r) {
        int row = bm + w * 32 + mf * 16 + q4 * 4 + r;
        C[(size_t)row * N + col] = acc[mf][nf][r] + bb;
      }
    }
}

extern "C" void kernel_launch(void* const* d_in, const int* in_sizes, int n_in,
                              void* d_out, int out_size, void* d_ws, size_t ws_size,
                              hipStream_t stream) {
  const float* x  = (const float*)d_in[0];
  const float* wq = (const float*)d_in[1];
  const float* bq = (const float*)d_in[2];
  const float* wk = (const float*)d_in[3];
  const float* bk = (const float*)d_in[4];
  const float* wv = (const float*)d_in[5];
  const float* bv = (const float*)d_in[6];
  const float* wo = (const float*)d_in[7];
  const float* bo = (const float*)d_in[8];
  float* out = (float*)d_out;
  const int B = in_sizes[0] / (1024 * 2048);
  const int M = B * 1024;

  char* ws = (char*)d_ws;
  size_t off = 0;
  auto alloc = [&](size_t bytes) -> char* {
    char* p = ws + off;
    off += (bytes + 255) & ~(size_t)255;
    return p;
  };
  short* xb    = (short*)alloc((size_t)M * 2048 * 2);
  short* WqkvT = (short*)alloc((size_t)3072 * 2048 * 2);  // rows: wq^T | wk^T | wv^T (K-major)
  short* woT   = (short*)alloc((size_t)2048 * 2048 * 2);
  short* Qb    = (short*)alloc((size_t)B * 32 * 1024 * 64 * 2);    // (b,h,t,d)
  short* Kb    = (short*)alloc((size_t)B * 8 * 2 * 1024 * 32 * 2); // (b,hkv)[dhalf][t][32]
  short* VTb   = (short*)alloc((size_t)B * 8 * 32 * 64 * 32 * 2);  // (b,hkv)[tchunk][d][32]
  short* AO    = (short*)alloc((size_t)M * 2048 * 2);              // (b,t,E) bf16

  const int n4 = M * 2048 / 4;
  const int nbc = (n4 + 255) / 256;
  prep_all<<<dim3(80 + (nbc + 31) / 32, 32), 256, 0, stream>>>(x, wq, wk, wv, wo, xb, WqkvT, woT, n4);
  gemm_qkv<<<dim3(48, M / 128), 256, 0, stream>>>(xb, WqkvT, bq, bk, bv, Qb, Kb, VTb);
  attn10_kernel<<<dim3(8, 32, B), 256, 0, stream>>>(Qb, Kb, VTb, AO);
  gemm_out<<<dim3(32, M / 128), 256, 0, stream>>>(AO, woT, out, bo, 2048, 2048);
}